// Round 1
// baseline (255.456 us; speedup 1.0000x reference)
//
#include <hip/hip_runtime.h>
#include <stdint.h>

#define B_SZ    4096
#define HEADS   16
#define HD      64
#define M_SZ    4096
#define K_IN    1024

typedef __bf16 bf16x8 __attribute__((ext_vector_type(8)));
typedef float  f32x4  __attribute__((ext_vector_type(4)));

union U16x8 {
    uint4 u4;
    unsigned short us[8];
    bf16x8 bf;
};

__device__ __forceinline__ unsigned short f2bf(float f) {
    uint32_t u = __builtin_bit_cast(uint32_t, f);
    u += 0x7FFFu + ((u >> 16) & 1u);   // round-to-nearest-even
    return (unsigned short)(u >> 16);
}

__device__ __forceinline__ bf16x8 ld_bf8_lds(const unsigned short* p) {
    U16x8 u;
    u.u4 = *reinterpret_cast<const uint4*>(p);
    return u.bf;
}

// ---------------------------------------------------------------------------
// Kernel 1: normalize memories -> Mn (bf16, [h][m][d]) and MnT (bf16, [h][d][m])
// grid (64, 16), block 256
// ---------------------------------------------------------------------------
__global__ __launch_bounds__(256) void k_prep_mem(const float* __restrict__ mem,
                                                  unsigned short* __restrict__ Mn,
                                                  unsigned short* __restrict__ MnT) {
    __shared__ float part[64][4];
    __shared__ float scale[64];
    __shared__ unsigned short T[64 * 72];   // [d][m] transposed tile, padded stride

    const int h  = blockIdx.y;
    const int m0 = blockIdx.x * 64;
    const int tid = threadIdx.x;
    const int r = tid >> 2;      // row within tile (memory index)
    const int c = tid & 3;       // 16-wide chunk of d

    const float* src = mem + ((size_t)(h * M_SZ + m0 + r)) * HD + c * 16;
    float v[16];
    float ss = 0.f;
#pragma unroll
    for (int i = 0; i < 4; i++) {
        float4 f = reinterpret_cast<const float4*>(src)[i];
        v[4*i+0] = f.x; v[4*i+1] = f.y; v[4*i+2] = f.z; v[4*i+3] = f.w;
        ss += f.x*f.x + f.y*f.y + f.z*f.z + f.w*f.w;
    }
    part[r][c] = ss;
    __syncthreads();
    if (tid < 64) {
        float s = part[tid][0] + part[tid][1] + part[tid][2] + part[tid][3];
        scale[tid] = rsqrtf(s);
    }
    __syncthreads();
    const float sc = scale[r];

    unsigned short ub[16];
#pragma unroll
    for (int i = 0; i < 16; i++) ub[i] = f2bf(v[i] * sc);

    // store Mn[h][m][d] (contiguous 32B per thread)
    unsigned short* dst = Mn + ((size_t)(h * M_SZ + m0 + r)) * HD + c * 16;
    U16x8 a, b;
#pragma unroll
    for (int i = 0; i < 8; i++) { a.us[i] = ub[i]; b.us[i] = ub[8 + i]; }
    reinterpret_cast<uint4*>(dst)[0] = a.u4;
    reinterpret_cast<uint4*>(dst)[1] = b.u4;

    // transpose through LDS
#pragma unroll
    for (int i = 0; i < 16; i++) T[(c * 16 + i) * 72 + r] = ub[i];
    __syncthreads();

    // coalesced write of MnT[h][d][m]
    const int d = tid >> 2;
    unsigned short* dstT = MnT + ((size_t)(h * HD + d)) * M_SZ + m0 + c * 16;
    uint4 t0 = *reinterpret_cast<const uint4*>(&T[d * 72 + c * 16]);
    uint4 t1 = *reinterpret_cast<const uint4*>(&T[d * 72 + c * 16 + 8]);
    reinterpret_cast<uint4*>(dstT)[0] = t0;
    reinterpret_cast<uint4*>(dstT)[1] = t1;
}

// ---------------------------------------------------------------------------
// Kernel 2: q = x @ W^T  (bf16 MFMA), fused per-head L2 normalize, write qn bf16
// grid (64, 16): x = 64-row tile of B, y = head (64-col tile). block 256 (4 waves)
// ---------------------------------------------------------------------------
__global__ __launch_bounds__(256) void k_qproj(const float* __restrict__ x,
                                               const float* __restrict__ Wq,
                                               unsigned short* __restrict__ qn) {
    __shared__ unsigned short As[64 * 72];
    __shared__ unsigned short Bs[64 * 72];

    const int b0 = blockIdx.x * 64;
    const int n0 = blockIdx.y * 64;     // == h*64
    const int tid = threadIdx.x;
    const int r = tid >> 2, c = tid & 3;
    const int w = tid >> 6, lane = tid & 63;
    const int l15 = lane & 15, quad = lane >> 4;

    f32x4 acc[4] = {};   // 16 rows (this wave) x 64 cols

    for (int kb = 0; kb < K_IN; kb += 64) {
        // ---- stage A and B tiles (f32 -> bf16 during staging) ----
        {
            const float* ax = x  + (size_t)(b0 + r) * K_IN + kb + c * 16;
            const float* bw = Wq + (size_t)(n0 + r) * K_IN + kb + c * 16;
            U16x8 p0, p1, q0, q1;
#pragma unroll
            for (int i = 0; i < 2; i++) {
                float4 f = reinterpret_cast<const float4*>(ax)[i];
                p0.us[4*i+0] = f2bf(f.x); p0.us[4*i+1] = f2bf(f.y);
                p0.us[4*i+2] = f2bf(f.z); p0.us[4*i+3] = f2bf(f.w);
                float4 g = reinterpret_cast<const float4*>(ax)[i + 2];
                p1.us[4*i+0] = f2bf(g.x); p1.us[4*i+1] = f2bf(g.y);
                p1.us[4*i+2] = f2bf(g.z); p1.us[4*i+3] = f2bf(g.w);
                float4 h = reinterpret_cast<const float4*>(bw)[i];
                q0.us[4*i+0] = f2bf(h.x); q0.us[4*i+1] = f2bf(h.y);
                q0.us[4*i+2] = f2bf(h.z); q0.us[4*i+3] = f2bf(h.w);
                float4 e = reinterpret_cast<const float4*>(bw)[i + 2];
                q1.us[4*i+0] = f2bf(e.x); q1.us[4*i+1] = f2bf(e.y);
                q1.us[4*i+2] = f2bf(e.z); q1.us[4*i+3] = f2bf(e.w);
            }
            *reinterpret_cast<uint4*>(&As[r * 72 + c * 16])     = p0.u4;
            *reinterpret_cast<uint4*>(&As[r * 72 + c * 16 + 8]) = p1.u4;
            *reinterpret_cast<uint4*>(&Bs[r * 72 + c * 16])     = q0.u4;
            *reinterpret_cast<uint4*>(&Bs[r * 72 + c * 16 + 8]) = q1.u4;
        }
        __syncthreads();

        // ---- MFMA: this wave's 16-row strip x all 64 cols ----
        bf16x8 afr0 = ld_bf8_lds(&As[(w * 16 + l15) * 72 + quad * 8]);
        bf16x8 afr1 = ld_bf8_lds(&As[(w * 16 + l15) * 72 + 32 + quad * 8]);
#pragma unroll
        for (int g = 0; g < 4; g++) {
            bf16x8 b0f = ld_bf8_lds(&Bs[(g * 16 + l15) * 72 + quad * 8]);
            acc[g] = __builtin_amdgcn_mfma_f32_16x16x32_bf16(afr0, b0f, acc[g], 0, 0, 0);
            bf16x8 b1f = ld_bf8_lds(&Bs[(g * 16 + l15) * 72 + 32 + quad * 8]);
            acc[g] = __builtin_amdgcn_mfma_f32_16x16x32_bf16(afr1, b1f, acc[g], 0, 0, 0);
        }
        __syncthreads();
    }

    // ---- fused per-head L2 normalization ----
    // C/D layout: col = l15 (+16g), row = quad*4 + reg. Row sum-of-squares needs
    // reduction over 4 frags (lane-local) then over the 16 lanes of this quad.
    float ssq[4];
#pragma unroll
    for (int reg = 0; reg < 4; reg++) {
        float s = 0.f;
#pragma unroll
        for (int g = 0; g < 4; g++) s += acc[g][reg] * acc[g][reg];
        ssq[reg] = s;
    }
#pragma unroll
    for (int mask = 1; mask <= 8; mask <<= 1) {
#pragma unroll
        for (int reg = 0; reg < 4; reg++)
            ssq[reg] += __shfl_xor(ssq[reg], mask, 64);
    }
    float inv[4];
#pragma unroll
    for (int reg = 0; reg < 4; reg++) inv[reg] = rsqrtf(ssq[reg]);

    // write normalized bf16 tile through LDS (reuse As) for coalesced store
    unsigned short* Ct = As;
#pragma unroll
    for (int g = 0; g < 4; g++)
#pragma unroll
        for (int reg = 0; reg < 4; reg++)
            Ct[(w * 16 + quad * 4 + reg) * 72 + g * 16 + l15] = f2bf(acc[g][reg] * inv[reg]);
    __syncthreads();

    unsigned short* dst = qn + (size_t)(b0 + r) * 1024 + n0 + c * 16;
    uint4 t0 = *reinterpret_cast<const uint4*>(&Ct[r * 72 + c * 16]);
    uint4 t1 = *reinterpret_cast<const uint4*>(&Ct[r * 72 + c * 16 + 8]);
    reinterpret_cast<uint4*>(dst)[0] = t0;
    reinterpret_cast<uint4*>(dst)[1] = t1;
}

// ---------------------------------------------------------------------------
// Kernel 3: fused attention readout. grid (64, 16): x = 64-query tile, y = head.
// block 256 = 4 waves, each wave owns 16 queries. No max-subtraction needed:
// scores are cosines in [-1,1].
// ---------------------------------------------------------------------------
__global__ __launch_bounds__(256) void k_attn(const unsigned short* __restrict__ qn,
                                              const unsigned short* __restrict__ Mn,
                                              const unsigned short* __restrict__ MnT,
                                              float* __restrict__ out) {
    __shared__ unsigned short Ms[64 * 72];       // [m][d]
    __shared__ unsigned short Ts[64 * 72];       // [d][m]
    __shared__ unsigned short Ps[4][16 * 72];    // per-wave P tile [q][m]

    const int b0 = blockIdx.x * 64;
    const int h  = blockIdx.y;
    const int tid = threadIdx.x;
    const int r = tid >> 2, c = tid & 3;
    const int w = tid >> 6, lane = tid & 63;
    const int l15 = lane & 15, quad = lane >> 4;

    // load this wave's Q fragments once (A-operand layout: m=l15, k=quad*8+j)
    const unsigned short* qp = qn + (size_t)(b0 + w * 16 + l15) * 1024 + h * 64 + quad * 8;
    bf16x8 qa0, qa1;
    { U16x8 u; u.u4 = *reinterpret_cast<const uint4*>(qp);      qa0 = u.bf; }
    { U16x8 u; u.u4 = *reinterpret_cast<const uint4*>(qp + 32); qa1 = u.bf; }

    f32x4 accO[4] = {};
    float lsum[4] = {0.f, 0.f, 0.f, 0.f};

    for (int m0 = 0; m0 < M_SZ; m0 += 64) {
        __syncthreads();   // protect Ms/Ts from previous iteration's readers
        // ---- stage Mn tile and MnT tile ----
        {
            const unsigned short* pm = Mn + (size_t)(h * M_SZ + m0 + r) * HD + c * 16;
            *reinterpret_cast<uint4*>(&Ms[r * 72 + c * 16])     = reinterpret_cast<const uint4*>(pm)[0];
            *reinterpret_cast<uint4*>(&Ms[r * 72 + c * 16 + 8]) = reinterpret_cast<const uint4*>(pm)[1];
            const unsigned short* pt = MnT + (size_t)(h * HD + r) * M_SZ + m0 + c * 16;
            *reinterpret_cast<uint4*>(&Ts[r * 72 + c * 16])     = reinterpret_cast<const uint4*>(pt)[0];
            *reinterpret_cast<uint4*>(&Ts[r * 72 + c * 16 + 8]) = reinterpret_cast<const uint4*>(pt)[1];
        }
        __syncthreads();

        // ---- S = Qn . Mn^T  (16 q x 64 m per wave) ----
        f32x4 sacc[4] = {};
#pragma unroll
        for (int g = 0; g < 4; g++) {
            bf16x8 b0f = ld_bf8_lds(&Ms[(g * 16 + l15) * 72 + quad * 8]);
            sacc[g] = __builtin_amdgcn_mfma_f32_16x16x32_bf16(qa0, b0f, sacc[g], 0, 0, 0);
            bf16x8 b1f = ld_bf8_lds(&Ms[(g * 16 + l15) * 72 + 32 + quad * 8]);
            sacc[g] = __builtin_amdgcn_mfma_f32_16x16x32_bf16(qa1, b1f, sacc[g], 0, 0, 0);
        }

        // ---- P = exp(S); accumulate row sums; write P to LDS in C-layout ----
#pragma unroll
        for (int g = 0; g < 4; g++) {
#pragma unroll
            for (int reg = 0; reg < 4; reg++) {
                float p = __expf(sacc[g][reg]);
                lsum[reg] += p;
                Ps[w][(quad * 4 + reg) * 72 + g * 16 + l15] = f2bf(p);
            }
        }
        __syncthreads();   // conservative: ensure P writes land before A-layout reads

        // ---- O += P . Mn  (A = P from LDS in A-layout, B = MnT tile) ----
#pragma unroll
        for (int s = 0; s < 2; s++) {
            bf16x8 pa = ld_bf8_lds(&Ps[w][l15 * 72 + s * 32 + quad * 8]);
#pragma unroll
            for (int g = 0; g < 4; g++) {
                bf16x8 bt = ld_bf8_lds(&Ts[(g * 16 + l15) * 72 + s * 32 + quad * 8]);
                accO[g] = __builtin_amdgcn_mfma_f32_16x16x32_bf16(pa, bt, accO[g], 0, 0, 0);
            }
        }
    }

    // ---- epilogue: normalize by row sum, scale by sqrt(64)=8, store f32 ----
#pragma unroll
    for (int mask = 1; mask <= 8; mask <<= 1) {
#pragma unroll
        for (int reg = 0; reg < 4; reg++)
            lsum[reg] += __shfl_xor(lsum[reg], mask, 64);
    }
    float inv[4];
#pragma unroll
    for (int reg = 0; reg < 4; reg++) inv[reg] = 8.0f / lsum[reg];

#pragma unroll
    for (int g = 0; g < 4; g++) {
#pragma unroll
        for (int reg = 0; reg < 4; reg++) {
            out[(size_t)(b0 + w * 16 + quad * 4 + reg) * 1024 + h * 64 + g * 16 + l15] =
                accO[g][reg] * inv[reg];
        }
    }
}

// ---------------------------------------------------------------------------
extern "C" void kernel_launch(void* const* d_in, const int* in_sizes, int n_in,
                              void* d_out, int out_size, void* d_ws, size_t ws_size,
                              hipStream_t stream) {
    (void)in_sizes; (void)n_in; (void)out_size; (void)ws_size;
    const float* x   = (const float*)d_in[0];
    const float* Wq  = (const float*)d_in[1];
    const float* mem = (const float*)d_in[2];
    float* out = (float*)d_out;

    unsigned short* qn  = (unsigned short*)d_ws;                  // 4096*1024 bf16 = 8 MB
    unsigned short* Mn  = qn + (size_t)B_SZ * 1024;               // 16*4096*64 bf16 = 8 MB
    unsigned short* MnT = Mn + (size_t)HEADS * M_SZ * HD;         // 8 MB

    dim3 grid(64, 16), blk(256);
    k_prep_mem<<<grid, blk, 0, stream>>>(mem, Mn, MnT);
    k_qproj  <<<grid, blk, 0, stream>>>(x, Wq, qn);
    k_attn   <<<grid, blk, 0, stream>>>(qn, Mn, MnT, out);
}

// Round 3
// 223.969 us; speedup vs baseline: 1.1406x; 1.1406x over previous
//
#include <hip/hip_runtime.h>
#include <stdint.h>

#define B_SZ  4096
#define HEADS 16
#define HD    64
#define M_SZ  4096
#define K_IN  1024
#define SW    72    // padded LDS row stride (f16 elems); 144B rows keep b128 16B-aligned

typedef _Float16 f16;
typedef f16  f16x4 __attribute__((ext_vector_type(4)));
typedef f16  f16x8 __attribute__((ext_vector_type(8)));
typedef float f32x4 __attribute__((ext_vector_type(4)));

union U8 { uint4 u4; f16x8 h8; unsigned short us[8]; };
union U4 { uint2 u2; f16x4 h4; unsigned short us[4]; };

__device__ __forceinline__ unsigned short f2h(float f) {
    _Float16 h = (_Float16)f;
    return __builtin_bit_cast(unsigned short, h);
}
__device__ __forceinline__ f16x8 ldsv8(const unsigned short* p) {
    U8 u; u.u4 = *reinterpret_cast<const uint4*>(p); return u.h8;
}

// ---------------------------------------------------------------------------
// Kernel 1: normalize memories and emit MFMA-fragment-ordered arrays:
//   Af[h][tile][g(4)][s(2)][lane(64)][j(8)]  f16  (A-operand of 16x16x32 QK^T)
//       element = Mn[m0+g*16+(lane&15)][d = s*32+(lane>>4)*8+j]
//   Bf[h][tile][g(4)][n(4)][lane(64)][j(4)]  f16  (B-operand of 16x16x16 PV)
//       element = Mn[m0+g*16+(lane>>4)*4+j][d = n*16+(lane&15)]
// grid (64, 16), block 256
// ---------------------------------------------------------------------------
__global__ __launch_bounds__(256) void k_prep_mem(const float* __restrict__ mem,
                                                  unsigned short* __restrict__ Af,
                                                  unsigned short* __restrict__ Bf) {
    __shared__ float part[64][4];
    __shared__ float scale[64];
    __shared__ unsigned short Tn[64 * SW];   // normalized tile, [m][d]

    const int h  = blockIdx.y;
    const int tl = blockIdx.x;
    const int m0 = tl * 64;
    const int tid = threadIdx.x;
    const int r = tid >> 2;
    const int c = tid & 3;

    const float* src = mem + ((size_t)(h * M_SZ + m0 + r)) * HD + c * 16;
    float v[16];
    float ss = 0.f;
#pragma unroll
    for (int i = 0; i < 4; i++) {
        float4 f = reinterpret_cast<const float4*>(src)[i];
        v[4*i+0] = f.x; v[4*i+1] = f.y; v[4*i+2] = f.z; v[4*i+3] = f.w;
        ss += f.x*f.x + f.y*f.y + f.z*f.z + f.w*f.w;
    }
    part[r][c] = ss;
    __syncthreads();
    if (tid < 64) {
        float s = part[tid][0] + part[tid][1] + part[tid][2] + part[tid][3];
        scale[tid] = rsqrtf(s);
    }
    __syncthreads();
    const float sc = scale[r];

    U8 a, b;
#pragma unroll
    for (int i = 0; i < 8; i++) { a.us[i] = f2h(v[i] * sc); b.us[i] = f2h(v[8 + i] * sc); }
    *reinterpret_cast<uint4*>(&Tn[r * SW + c * 16])     = a.u4;
    *reinterpret_cast<uint4*>(&Tn[r * SW + c * 16 + 8]) = b.u4;
    __syncthreads();

    const int w = tid >> 6, lane = tid & 63;
    const int l15 = lane & 15, quad = lane >> 4;

    // Af: each wave handles 2 of the 8 (g,s) combos
#pragma unroll
    for (int i = 0; i < 2; i++) {
        const int gs = w * 2 + i, g = gs >> 1, s = gs & 1;
        uint4 vv = *reinterpret_cast<const uint4*>(&Tn[(g * 16 + l15) * SW + s * 32 + quad * 8]);
        unsigned short* dst = Af + (((size_t)(h * 64 + tl) * 8 + gs) * 64 + lane) * 8;
        *reinterpret_cast<uint4*>(dst) = vv;
    }
    // Bf: each wave handles 4 of the 16 (g,n) combos
#pragma unroll
    for (int i = 0; i < 4; i++) {
        const int gn = w * 4 + i, g = gn >> 2, n = gn & 3;
        U4 u;
#pragma unroll
        for (int j = 0; j < 4; j++)
            u.us[j] = Tn[(g * 16 + quad * 4 + j) * SW + n * 16 + l15];
        unsigned short* dst = Bf + (((size_t)(h * 64 + tl) * 16 + gn) * 64 + lane) * 4;
        *reinterpret_cast<uint2*>(dst) = u.u2;
    }
}

// ---------------------------------------------------------------------------
// Kernel 2: q = x @ W^T (f16 MFMA, 128x64 tile), fused per-head L2 norm -> qn f16
// grid (32, 16): x = 128-row tile, y = head. block 256 (4 waves, 32 rows each)
// ---------------------------------------------------------------------------
__global__ __launch_bounds__(256, 2) void k_qproj(const float* __restrict__ x,
                                                  const float* __restrict__ Wq,
                                                  unsigned short* __restrict__ qn) {
    __shared__ unsigned short As[128 * SW];
    __shared__ unsigned short Bs[64 * SW];

    const int b0 = blockIdx.x * 128;
    const int n0 = blockIdx.y * 64;
    const int t = threadIdx.x;
    const int w = t >> 6, lane = t & 63;
    const int l15 = lane & 15, quad = lane >> 4;

    f32x4 acc[2][4] = {};

    for (int kb = 0; kb < K_IN; kb += 64) {
        __syncthreads();
        {
            const int ra = t >> 1, ka = (t & 1) * 32;
            const float* px = x + (size_t)(b0 + ra) * K_IN + kb + ka;
            U8 pk[4];
#pragma unroll
            for (int i = 0; i < 4; i++) {
                float4 f0 = reinterpret_cast<const float4*>(px)[2*i];
                float4 f1 = reinterpret_cast<const float4*>(px)[2*i+1];
                pk[i].us[0]=f2h(f0.x); pk[i].us[1]=f2h(f0.y); pk[i].us[2]=f2h(f0.z); pk[i].us[3]=f2h(f0.w);
                pk[i].us[4]=f2h(f1.x); pk[i].us[5]=f2h(f1.y); pk[i].us[6]=f2h(f1.z); pk[i].us[7]=f2h(f1.w);
            }
#pragma unroll
            for (int i = 0; i < 4; i++)
                *reinterpret_cast<uint4*>(&As[ra * SW + ka + i * 8]) = pk[i].u4;

            const int rb = t >> 2, cb = (t & 3) * 16;
            const float* pw = Wq + (size_t)(n0 + rb) * K_IN + kb + cb;
            U8 qk[2];
#pragma unroll
            for (int i = 0; i < 2; i++) {
                float4 f0 = reinterpret_cast<const float4*>(pw)[2*i];
                float4 f1 = reinterpret_cast<const float4*>(pw)[2*i+1];
                qk[i].us[0]=f2h(f0.x); qk[i].us[1]=f2h(f0.y); qk[i].us[2]=f2h(f0.z); qk[i].us[3]=f2h(f0.w);
                qk[i].us[4]=f2h(f1.x); qk[i].us[5]=f2h(f1.y); qk[i].us[6]=f2h(f1.z); qk[i].us[7]=f2h(f1.w);
            }
            *reinterpret_cast<uint4*>(&Bs[rb * SW + cb])     = qk[0].u4;
            *reinterpret_cast<uint4*>(&Bs[rb * SW + cb + 8]) = qk[1].u4;
        }
        __syncthreads();

        f16x8 af[2][2];
#pragma unroll
        for (int qg = 0; qg < 2; qg++)
#pragma unroll
            for (int s = 0; s < 2; s++)
                af[qg][s] = ldsv8(&As[(w * 32 + qg * 16 + l15) * SW + s * 32 + quad * 8]);

#pragma unroll
        for (int g = 0; g < 4; g++) {
#pragma unroll
            for (int s = 0; s < 2; s++) {
                f16x8 bf_ = ldsv8(&Bs[(g * 16 + l15) * SW + s * 32 + quad * 8]);
#pragma unroll
                for (int qg = 0; qg < 2; qg++)
                    acc[qg][g] = __builtin_amdgcn_mfma_f32_16x16x32_f16(af[qg][s], bf_, acc[qg][g], 0, 0, 0);
            }
        }
    }

    __syncthreads();
    unsigned short* Ct = As;
#pragma unroll
    for (int qg = 0; qg < 2; qg++) {
        float ssq[4];
#pragma unroll
        for (int r = 0; r < 4; r++) {
            float s = 0.f;
#pragma unroll
            for (int g = 0; g < 4; g++) s += acc[qg][g][r] * acc[qg][g][r];
            ssq[r] = s;
        }
#pragma unroll
        for (int mask = 1; mask <= 8; mask <<= 1)
#pragma unroll
            for (int r = 0; r < 4; r++) ssq[r] += __shfl_xor(ssq[r], mask, 64);
#pragma unroll
        for (int r = 0; r < 4; r++) {
            float inv = rsqrtf(ssq[r]);
#pragma unroll
            for (int g = 0; g < 4; g++)
                Ct[(w * 32 + qg * 16 + quad * 4 + r) * SW + g * 16 + l15] = f2h(acc[qg][g][r] * inv);
        }
    }
    __syncthreads();

    const int r = t >> 1, cc = (t & 1) * 32;
    unsigned short* dq = qn + (size_t)(b0 + r) * 1024 + n0 + cc;
#pragma unroll
    for (int i = 0; i < 4; i++)
        reinterpret_cast<uint4*>(dq)[i] = *reinterpret_cast<const uint4*>(&Ct[r * SW + cc + i * 8]);
}

// ---------------------------------------------------------------------------
// Kernel 3: fused attention readout. ZERO LDS, zero barriers — race-free by
// construction. grid 256 blocks; XCD-aware swizzle keeps each head's 1 MB of
// fragment data resident in one XCD's L2. Each block: 256 queries x 1 head;
// 4 waves x 64 q each. Fragments stream straight from global (L1/L2).
// ---------------------------------------------------------------------------
__global__ __launch_bounds__(256, 1) void k_attn(const unsigned short* __restrict__ qn,
                                                 const unsigned short* __restrict__ Af,
                                                 const unsigned short* __restrict__ Bf,
                                                 float* __restrict__ out) {
    const int b = blockIdx.x;
    const int h  = 2 * (b & 7) + (b >> 7);     // blocks ≡k (mod 8) -> heads {2k,2k+1}
    const int b0 = ((b >> 3) & 15) * 256;
    const int t = threadIdx.x;
    const int w = t >> 6, lane = t & 63;
    const int l15 = lane & 15, quad = lane >> 4;

    // Q as B-operand of 16x16x32 (lane holds Q[q=l15][d=s*32+quad*8+j])
    f16x8 qf[4][2];
#pragma unroll
    for (int qg = 0; qg < 4; qg++)
#pragma unroll
        for (int s = 0; s < 2; s++) {
            U8 u;
            u.u4 = *reinterpret_cast<const uint4*>(
                qn + (size_t)(b0 + w * 64 + qg * 16 + l15) * 1024 + h * 64 + s * 32 + quad * 8);
            qf[qg][s] = u.h8;
        }

    const unsigned short* pAh = Af + (size_t)h * 64 * 8 * 64 * 8 + lane * 8;
    const unsigned short* pBh = Bf + (size_t)h * 64 * 16 * 64 * 4 + lane * 4;

    f32x4 accO[4][4] = {};
    float lsum[4] = {0.f, 0.f, 0.f, 0.f};

    for (int tl = 0; tl < 64; ++tl) {
        const unsigned short* pAt = pAh + (size_t)tl * (8 * 64 * 8);
        const unsigned short* pBt = pBh + (size_t)tl * (16 * 64 * 4);

        f16x8 am[8];
#pragma unroll
        for (int gs = 0; gs < 8; gs++) {
            U8 u; u.u4 = *reinterpret_cast<const uint4*>(pAt + gs * 512);
            am[gs] = u.h8;
        }
        f16x4 bv[16];
#pragma unroll
        for (int gn = 0; gn < 16; gn++) {
            U4 u; u.u2 = *reinterpret_cast<const uint2*>(pBt + gn * 256);
            bv[gn] = u.h4;
        }

        // S^T = M . Q^T : lane holds S[q=l15][m = 64*tl + g*16 + quad*4 + reg]
        f16x4 pa[4][4];
#pragma unroll
        for (int qg = 0; qg < 4; qg++) {
#pragma unroll
            for (int g = 0; g < 4; g++) {
                f32x4 sc = {0.f, 0.f, 0.f, 0.f};
                sc = __builtin_amdgcn_mfma_f32_16x16x32_f16(am[g * 2 + 0], qf[qg][0], sc, 0, 0, 0);
                sc = __builtin_amdgcn_mfma_f32_16x16x32_f16(am[g * 2 + 1], qf[qg][1], sc, 0, 0, 0);
                float p0 = __expf(sc[0]), p1 = __expf(sc[1]);
                float p2 = __expf(sc[2]), p3 = __expf(sc[3]);
                lsum[qg] += (p0 + p1) + (p2 + p3);
                f16x4 pp;
                pp[0] = (f16)p0; pp[1] = (f16)p1; pp[2] = (f16)p2; pp[3] = (f16)p3;
                pa[qg][g] = pp;   // A-frag of 16x16x16: A[q=l15][k=quad*4+j]
            }
        }

        // O += P . V
#pragma unroll
        for (int g = 0; g < 4; g++)
#pragma unroll
            for (int n = 0; n < 4; n++)
#pragma unroll
                for (int qg = 0; qg < 4; qg++)
                    accO[qg][n] = __builtin_amdgcn_mfma_f32_16x16x16f16(pa[qg][g], bv[g * 4 + n], accO[qg][n], 0, 0, 0);
    }

    // epilogue: reduce lsum over quads (lanes with same l15), normalize, store
#pragma unroll
    for (int qg = 0; qg < 4; qg++) {
        float s = lsum[qg];
        s += __shfl_xor(s, 16, 64);
        s += __shfl_xor(s, 32, 64);
        float inv = 8.0f / s;    // sqrt(HEAD_DIM)=8
#pragma unroll
        for (int r = 0; r < 4; r++) {
            float iv = __shfl(inv, quad * 4 + r, 64);
            float* po = out + (size_t)(b0 + w * 64 + qg * 16 + quad * 4 + r) * 1024 + h * 64;
#pragma unroll
            for (int n = 0; n < 4; n++)
                po[n * 16 + l15] = accO[qg][n][r] * iv;
        }
    }
}

// ---------------------------------------------------------------------------
extern "C" void kernel_launch(void* const* d_in, const int* in_sizes, int n_in,
                              void* d_out, int out_size, void* d_ws, size_t ws_size,
                              hipStream_t stream) {
    (void)in_sizes; (void)n_in; (void)out_size; (void)ws_size;
    const float* x   = (const float*)d_in[0];
    const float* Wq  = (const float*)d_in[1];
    const float* mem = (const float*)d_in[2];
    float* out = (float*)d_out;

    unsigned short* qn = (unsigned short*)d_ws;               // 8 MB
    unsigned short* Af = qn + (size_t)B_SZ * 1024;            // 8 MB (frag-ordered A)
    unsigned short* Bf = Af + (size_t)HEADS * 64 * 8 * 64 * 8;// 8 MB (frag-ordered B)

    k_prep_mem<<<dim3(64, 16), 256, 0, stream>>>(mem, Af, Bf);
    k_qproj  <<<dim3(32, 16), 256, 0, stream>>>(x, Wq, qn);
    k_attn   <<<256, 256, 0, stream>>>(qn, Af, Bf, out);
}

// Round 5
// 199.008 us; speedup vs baseline: 1.2836x; 1.1254x over previous
//
#include <hip/hip_runtime.h>
#include <stdint.h>

#define B_SZ  4096
#define HEADS 16
#define HD    64
#define M_SZ  4096
#define K_IN  1024
#define SW    72    // padded LDS row stride (f16 elems)
#define LOG2E 1.44269504088896f

typedef _Float16 f16;
typedef f16  f16x2 __attribute__((ext_vector_type(2)));
typedef f16  f16x4 __attribute__((ext_vector_type(4)));
typedef f16  f16x8 __attribute__((ext_vector_type(8)));
typedef float f32x4 __attribute__((ext_vector_type(4)));

union U8 { uint4 u4; f16x8 h8; unsigned short us[8]; };
union U4 { uint2 u2; f16x4 h4; unsigned int ui[2]; unsigned short us[4]; };

__device__ __forceinline__ unsigned short f2h(float f) {
    _Float16 h = (_Float16)f;
    return __builtin_bit_cast(unsigned short, h);
}
__device__ __forceinline__ f16x8 ldsv8(const unsigned short* p) {
    U8 u; u.u4 = *reinterpret_cast<const uint4*>(p); return u.h8;
}

#if __has_builtin(__builtin_amdgcn_exp2f)
#define EXP2F(x) __builtin_amdgcn_exp2f(x)
#else
#define EXP2F(x) __expf((x) * 0.6931471805599453f)
#endif

__device__ __forceinline__ f16x4 pack4(float a, float b, float c, float d) {
#if __has_builtin(__builtin_amdgcn_cvt_pkrtz)
    U4 u;
    u.ui[0] = __builtin_bit_cast(unsigned int, __builtin_amdgcn_cvt_pkrtz(a, b));
    u.ui[1] = __builtin_bit_cast(unsigned int, __builtin_amdgcn_cvt_pkrtz(c, d));
    return u.h4;
#else
    f16x4 r; r[0] = (f16)a; r[1] = (f16)b; r[2] = (f16)c; r[3] = (f16)d;
    return r;
#endif
}

// ---------------------------------------------------------------------------
// Kernel 0: f32 -> f16 conversion of x and Wq (one pass).
// blocks [0,2048): x (4M elems); [2048,2560): Wq (1M elems). 8 f32/thread.
// ---------------------------------------------------------------------------
__global__ __launch_bounds__(256) void k_conv(const float* __restrict__ x,
                                              const float* __restrict__ Wq,
                                              unsigned short* __restrict__ xh,
                                              unsigned short* __restrict__ Wh) {
    const int b = blockIdx.x;
    const float* src;
    unsigned short* dst;
    size_t base;
    if (b < 2048) { src = x;  dst = xh; base = (size_t)b * 2048; }
    else          { src = Wq; dst = Wh; base = (size_t)(b - 2048) * 2048; }
    const size_t i = base + (size_t)threadIdx.x * 8;
    float4 f0 = reinterpret_cast<const float4*>(src + i)[0];
    float4 f1 = reinterpret_cast<const float4*>(src + i)[1];
    U8 u;
    u.us[0] = f2h(f0.x); u.us[1] = f2h(f0.y); u.us[2] = f2h(f0.z); u.us[3] = f2h(f0.w);
    u.us[4] = f2h(f1.x); u.us[5] = f2h(f1.y); u.us[6] = f2h(f1.z); u.us[7] = f2h(f1.w);
    *reinterpret_cast<uint4*>(dst + i) = u.u4;
}

// ---------------------------------------------------------------------------
// Kernel 1: normalize memories, emit MFMA-fragment-ordered arrays:
//   Af[h][tile][gs(8)][lane(64)][8]  (A-operand of 16x16x32 QK^T)
//       gs = g*2+s: elem = Mn[m0+g*16+(lane&15)][d = s*32+(lane>>4)*8+j]
//   Bf[h][tile][gnp(8)][lane(64)][8] (paired B-operands of 16x16x16 PV)
//       gnp = g*2+np: j<4 -> n=2np, j>=4 -> n=2np+1:
//       elem = Mn[m0+g*16+(lane>>4)*4+(j&3)][d = n*16+(lane&15)]
// grid (64, 16), block 256
// ---------------------------------------------------------------------------
__global__ __launch_bounds__(256) void k_prep_mem(const float* __restrict__ mem,
                                                  unsigned short* __restrict__ Af,
                                                  unsigned short* __restrict__ Bf) {
    __shared__ float part[64][4];
    __shared__ float scale[64];
    __shared__ unsigned short Tn[64 * SW];

    const int h  = blockIdx.y;
    const int tl = blockIdx.x;
    const int m0 = tl * 64;
    const int tid = threadIdx.x;
    const int r = tid >> 2;
    const int c = tid & 3;

    const float* src = mem + ((size_t)(h * M_SZ + m0 + r)) * HD + c * 16;
    float v[16];
    float ss = 0.f;
#pragma unroll
    for (int i = 0; i < 4; i++) {
        float4 f = reinterpret_cast<const float4*>(src)[i];
        v[4*i+0] = f.x; v[4*i+1] = f.y; v[4*i+2] = f.z; v[4*i+3] = f.w;
        ss += f.x*f.x + f.y*f.y + f.z*f.z + f.w*f.w;
    }
    part[r][c] = ss;
    __syncthreads();
    if (tid < 64) {
        float s = part[tid][0] + part[tid][1] + part[tid][2] + part[tid][3];
        scale[tid] = rsqrtf(s);
    }
    __syncthreads();
    const float sc = scale[r];

    U8 a, b;
#pragma unroll
    for (int i = 0; i < 8; i++) { a.us[i] = f2h(v[i] * sc); b.us[i] = f2h(v[8 + i] * sc); }
    *reinterpret_cast<uint4*>(&Tn[r * SW + c * 16])     = a.u4;
    *reinterpret_cast<uint4*>(&Tn[r * SW + c * 16 + 8]) = b.u4;
    __syncthreads();

    const int w = tid >> 6, lane = tid & 63;
    const int l15 = lane & 15, quad = lane >> 4;

    // Af: wave handles 2 of 8 (g,s) combos
#pragma unroll
    for (int i = 0; i < 2; i++) {
        const int gs = w * 2 + i, g = gs >> 1, s = gs & 1;
        uint4 vv = *reinterpret_cast<const uint4*>(&Tn[(g * 16 + l15) * SW + s * 32 + quad * 8]);
        unsigned short* dst = Af + (((size_t)(h * 64 + tl) * 8 + gs) * 64 + lane) * 8;
        *reinterpret_cast<uint4*>(dst) = vv;
    }
    // Bf: wave handles 2 of 8 (g,np) combos
#pragma unroll
    for (int i = 0; i < 2; i++) {
        const int gnp = w * 2 + i, g = gnp >> 1, np = gnp & 1;
        U8 u;
#pragma unroll
        for (int j = 0; j < 4; j++) {
            u.us[j]     = Tn[(g * 16 + quad * 4 + j) * SW + (2 * np) * 16 + l15];
            u.us[4 + j] = Tn[(g * 16 + quad * 4 + j) * SW + (2 * np + 1) * 16 + l15];
        }
        unsigned short* dst = Bf + (((size_t)(h * 64 + tl) * 8 + gnp) * 64 + lane) * 8;
        *reinterpret_cast<uint4*>(dst) = u.u4;
    }
}

// ---------------------------------------------------------------------------
// Kernel 2: q = xh @ Wh^T (f16 MFMA, 128x128 tile), fused per-head L2 norm,
// pre-scaled by log2(e) -> qn f16. grid (32, 8). block 256 = 4 waves (2x2),
// each wave computes a 64x64 sub-tile.
// ---------------------------------------------------------------------------
__global__ __launch_bounds__(256) void k_qproj(const unsigned short* __restrict__ xh,
                                               const unsigned short* __restrict__ Wh,
                                               unsigned short* __restrict__ qn) {
    __shared__ unsigned short sbuf[2 * 128 * SW];   // As | Bs, reused as Ct
    unsigned short* As = sbuf;
    unsigned short* Bs = sbuf + 128 * SW;

    const int b0 = blockIdx.x * 128;
    const int n0 = blockIdx.y * 128;
    const int t = threadIdx.x;
    const int w = t >> 6, lane = t & 63;
    const int wr = w >> 1, wc = w & 1;
    const int l15 = lane & 15, quad = lane >> 4;

    f32x4 acc[4][4] = {};   // [qg(row 16-group)][g(col 16-group)]

    const int sr = t >> 1, sh = (t & 1) * 32;
    for (int kb = 0; kb < K_IN; kb += 64) {
        __syncthreads();
        {
            const unsigned short* px = xh + (size_t)(b0 + sr) * K_IN + kb + sh;
            const unsigned short* pw = Wh + (size_t)(n0 + sr) * K_IN + kb + sh;
            uint4 av[4], bv[4];
#pragma unroll
            for (int i = 0; i < 4; i++) av[i] = reinterpret_cast<const uint4*>(px)[i];
#pragma unroll
            for (int i = 0; i < 4; i++) bv[i] = reinterpret_cast<const uint4*>(pw)[i];
#pragma unroll
            for (int i = 0; i < 4; i++) {
                *reinterpret_cast<uint4*>(&As[sr * SW + sh + i * 8]) = av[i];
                *reinterpret_cast<uint4*>(&Bs[sr * SW + sh + i * 8]) = bv[i];
            }
        }
        __syncthreads();

#pragma unroll
        for (int s = 0; s < 2; s++) {
            f16x8 af[4];
#pragma unroll
            for (int qg = 0; qg < 4; qg++)
                af[qg] = ldsv8(&As[(wr * 64 + qg * 16 + l15) * SW + s * 32 + quad * 8]);
#pragma unroll
            for (int g = 0; g < 4; g++) {
                f16x8 bf_ = ldsv8(&Bs[(wc * 64 + g * 16 + l15) * SW + s * 32 + quad * 8]);
#pragma unroll
                for (int qg = 0; qg < 4; qg++)
                    acc[qg][g] = __builtin_amdgcn_mfma_f32_16x16x32_f16(af[qg], bf_, acc[qg][g], 0, 0, 0);
            }
        }
    }

    // fused per-head L2 norm (each wave's 64 cols = one head), prescale log2e
    __syncthreads();
    unsigned short* Ct = sbuf;   // 128 x 136 layout
#pragma unroll
    for (int qg = 0; qg < 4; qg++) {
        float ssq[4];
#pragma unroll
        for (int r = 0; r < 4; r++) {
            float s = 0.f;
#pragma unroll
            for (int g = 0; g < 4; g++) s += acc[qg][g][r] * acc[qg][g][r];
            ssq[r] = s;
        }
#pragma unroll
        for (int mask = 1; mask <= 8; mask <<= 1)
#pragma unroll
            for (int r = 0; r < 4; r++) ssq[r] += __shfl_xor(ssq[r], mask, 64);
#pragma unroll
        for (int r = 0; r < 4; r++) {
            float inv = rsqrtf(ssq[r]) * LOG2E;
#pragma unroll
            for (int g = 0; g < 4; g++)
                Ct[(wr * 64 + qg * 16 + quad * 4 + r) * 136 + wc * 64 + g * 16 + l15] =
                    f2h(acc[qg][g][r] * inv);
        }
    }
    __syncthreads();

    const int row = t >> 1, half = (t & 1) * 64;
    unsigned short* dq = qn + (size_t)(b0 + row) * 1024 + n0 + half;
#pragma unroll
    for (int i = 0; i < 8; i++)
        reinterpret_cast<uint4*>(dq)[i] = *reinterpret_cast<const uint4*>(&Ct[row * 136 + half + i * 8]);
}

// ---------------------------------------------------------------------------
// Kernel 3: fused attention readout. Zero LDS / zero barriers. grid 512:
// 128 queries x 1 head per block; 4 waves x 32 q (2 groups of 16).
// launch_bounds(256,2) -> 2 blocks/CU, 2 waves/SIMD for latency overlap.
// qn is prescaled by log2e -> plain v_exp (exp2) softmax, cvt_pkrtz packing.
// ---------------------------------------------------------------------------
__global__ __launch_bounds__(256, 2) void k_attn(const unsigned short* __restrict__ qn,
                                                 const unsigned short* __restrict__ Af,
                                                 const unsigned short* __restrict__ Bf,
                                                 float* __restrict__ out) {
    const int b = blockIdx.x;
    const int h  = 2 * (b & 7) + (b >> 8);     // XCD k gets heads {2k, 2k+1}
    const int b0 = ((b >> 3) & 31) * 128;
    const int t = threadIdx.x;
    const int w = t >> 6, lane = t & 63;
    const int l15 = lane & 15, quad = lane >> 4;

    // Q as B-operand of 16x16x32 (lane holds Q[q=l15][d=s*32+quad*8+j])
    f16x8 qf[2][2];
#pragma unroll
    for (int qg = 0; qg < 2; qg++)
#pragma unroll
        for (int s = 0; s < 2; s++) {
            U8 u;
            u.u4 = *reinterpret_cast<const uint4*>(
                qn + (size_t)(b0 + w * 32 + qg * 16 + l15) * 1024 + h * 64 + s * 32 + quad * 8);
            qf[qg][s] = u.h8;
        }

    const unsigned short* pA = Af + (size_t)h * 64 * 4096 + lane * 8;
    const unsigned short* pB = Bf + (size_t)h * 64 * 4096 + lane * 8;

    f32x4 accO[2][4] = {};
    float lsum[2] = {0.f, 0.f};

    for (int tl = 0; tl < 64; ++tl) {
        const unsigned short* pAt = pA + (size_t)tl * 4096;
        const unsigned short* pBt = pB + (size_t)tl * 4096;

        f16x8 am[8], bw[8];
#pragma unroll
        for (int gs = 0; gs < 8; gs++) {
            U8 u; u.u4 = *reinterpret_cast<const uint4*>(pAt + gs * 512);
            am[gs] = u.h8;
        }
#pragma unroll
        for (int gnp = 0; gnp < 8; gnp++) {
            U8 u; u.u4 = *reinterpret_cast<const uint4*>(pBt + gnp * 512);
            bw[gnp] = u.h8;
        }

        // S^T = M . Q^T : lane holds S[q=l15][m = 64*tl + g*16 + quad*4 + reg]
        f16x4 pa[2][4];
#pragma unroll
        for (int qg = 0; qg < 2; qg++) {
#pragma unroll
            for (int g = 0; g < 4; g++) {
                f32x4 sc = {0.f, 0.f, 0.f, 0.f};
                sc = __builtin_amdgcn_mfma_f32_16x16x32_f16(am[g * 2 + 0], qf[qg][0], sc, 0, 0, 0);
                sc = __builtin_amdgcn_mfma_f32_16x16x32_f16(am[g * 2 + 1], qf[qg][1], sc, 0, 0, 0);
                float p0 = EXP2F(sc[0]), p1 = EXP2F(sc[1]);
                float p2 = EXP2F(sc[2]), p3 = EXP2F(sc[3]);
                lsum[qg] += (p0 + p1) + (p2 + p3);
                pa[qg][g] = pack4(p0, p1, p2, p3);   // A-frag: A[q=l15][k=quad*4+j]
            }
        }

        // O += P . V  (B-frags: bw[g*2+np] lo half = n=2np, hi half = n=2np+1)
#pragma unroll
        for (int g = 0; g < 4; g++) {
#pragma unroll
            for (int np = 0; np < 2; np++) {
                f16x4 blo = __builtin_shufflevector(bw[g * 2 + np], bw[g * 2 + np], 0, 1, 2, 3);
                f16x4 bhi = __builtin_shufflevector(bw[g * 2 + np], bw[g * 2 + np], 4, 5, 6, 7);
#pragma unroll
                for (int qg = 0; qg < 2; qg++) {
                    accO[qg][2 * np]     = __builtin_amdgcn_mfma_f32_16x16x16f16(pa[qg][g], blo, accO[qg][2 * np], 0, 0, 0);
                    accO[qg][2 * np + 1] = __builtin_amdgcn_mfma_f32_16x16x16f16(pa[qg][g], bhi, accO[qg][2 * np + 1], 0, 0, 0);
                }
            }
        }
    }

    // epilogue: reduce lsum over quads, normalize, store
#pragma unroll
    for (int qg = 0; qg < 2; qg++) {
        float s = lsum[qg];
        s += __shfl_xor(s, 16, 64);
        s += __shfl_xor(s, 32, 64);
        float inv = 8.0f / s;    // sqrt(HEAD_DIM)=8
#pragma unroll
        for (int r = 0; r < 4; r++) {
            float iv = __shfl(inv, quad * 4 + r, 64);
            float* po = out + (size_t)(b0 + w * 32 + qg * 16 + quad * 4 + r) * 1024 + h * 64;
#pragma unroll
            for (int n = 0; n < 4; n++)
                po[n * 16 + l15] = accO[qg][n][r] * iv;
        }
    }
}

// ---------------------------------------------------------------------------
extern "C" void kernel_launch(void* const* d_in, const int* in_sizes, int n_in,
                              void* d_out, int out_size, void* d_ws, size_t ws_size,
                              hipStream_t stream) {
    (void)in_sizes; (void)n_in; (void)out_size; (void)ws_size;
    const float* x   = (const float*)d_in[0];
    const float* Wq  = (const float*)d_in[1];
    const float* mem = (const float*)d_in[2];
    float* out = (float*)d_out;

    unsigned short* qn = (unsigned short*)d_ws;                 // 8 MB
    unsigned short* Af = qn + (size_t)B_SZ * 1024;              // 8 MB
    unsigned short* Bf = Af + (size_t)HEADS * 64 * 4096;        // 8 MB
    unsigned short* xh = Bf + (size_t)HEADS * 64 * 4096;        // 8 MB
    unsigned short* Wh = xh + (size_t)B_SZ * K_IN;              // 2 MB   (total 34 MB)

    k_conv    <<<2560, 256, 0, stream>>>(x, Wq, xh, Wh);
    k_prep_mem<<<dim3(64, 16), 256, 0, stream>>>(mem, Af, Bf);
    k_qproj   <<<dim3(32, 8), 256, 0, stream>>>(xh, Wh, qn);
    k_attn    <<<512, 256, 0, stream>>>(qn, Af, Bf, out);
}

// Round 6
// 179.139 us; speedup vs baseline: 1.4260x; 1.1109x over previous
//
#include <hip/hip_runtime.h>
#include <stdint.h>

#define B_SZ  4096
#define HEADS 16
#define HD    64
#define M_SZ  4096
#define K_IN  1024
#define SW    72    // padded LDS row stride (f16 elems)
#define LOG2E 1.44269504088896f

typedef _Float16 f16;
typedef f16  f16x4 __attribute__((ext_vector_type(4)));
typedef f16  f16x8 __attribute__((ext_vector_type(8)));
typedef float f32x4 __attribute__((ext_vector_type(4)));

union U8 { uint4 u4; f16x8 h8; unsigned int ui[4]; unsigned short us[8]; };

__device__ __forceinline__ unsigned short f2h(float f) {
    _Float16 h = (_Float16)f;
    return __builtin_bit_cast(unsigned short, h);
}
__device__ __forceinline__ f16x8 ldsv8(const unsigned short* p) {
    U8 u; u.u4 = *reinterpret_cast<const uint4*>(p); return u.h8;
}

#if __has_builtin(__builtin_amdgcn_exp2f)
#define EXP2F(x) __builtin_amdgcn_exp2f(x)
#else
#define EXP2F(x) __expf((x) * 0.6931471805599453f)
#endif

// async global -> LDS, 16 B per lane (lane i lands at ldsbase + i*16)
__device__ __forceinline__ void gload_lds16(const void* g, void* l) {
    __builtin_amdgcn_global_load_lds(
        (const __attribute__((address_space(1))) void*)g,
        (__attribute__((address_space(3))) void*)l, 16, 0, 0);
}

// ---------------------------------------------------------------------------
// Kernel 0: f32 -> f16 conversion of x and Wq (one pass).
// ---------------------------------------------------------------------------
__global__ __launch_bounds__(256) void k_conv(const float* __restrict__ x,
                                              const float* __restrict__ Wq,
                                              unsigned short* __restrict__ xh,
                                              unsigned short* __restrict__ Wh) {
    const int b = blockIdx.x;
    const float* src;
    unsigned short* dst;
    size_t base;
    if (b < 2048) { src = x;  dst = xh; base = (size_t)b * 2048; }
    else          { src = Wq; dst = Wh; base = (size_t)(b - 2048) * 2048; }
    const size_t i = base + (size_t)threadIdx.x * 8;
    float4 f0 = reinterpret_cast<const float4*>(src + i)[0];
    float4 f1 = reinterpret_cast<const float4*>(src + i)[1];
    U8 u;
    u.us[0] = f2h(f0.x); u.us[1] = f2h(f0.y); u.us[2] = f2h(f0.z); u.us[3] = f2h(f0.w);
    u.us[4] = f2h(f1.x); u.us[5] = f2h(f1.y); u.us[6] = f2h(f1.z); u.us[7] = f2h(f1.w);
    *reinterpret_cast<uint4*>(dst + i) = u.u4;
}

// ---------------------------------------------------------------------------
// Kernel 1: normalize memories, emit ONE fragment-ordered array
//   F[h][tile][chunk(16)][lane(64)][j(8)]  (16 KB per (h,tile))
// chunks 0..7  (gs = g*2+s): QK A-frag of 16x16x32 with PERMUTED m:
//   elem = Mn[m_phys(g, lane&15)][d = s*32 + (lane>>4)*8 + j]
//   m_phys(g, r) = 32*(g>>1) + (r>>2)*8 + 4*(g&1) + (r&3)
// chunks 8..15 (c2 = p*4+n): PV B-frag of 16x16x32 (physical m = k):
//   elem = Mn[32*p + (lane>>4)*8 + j][d = n*16 + (lane&15)]
// After QK(+exp), lane's regs {g=2p: r0..3, g=2p+1: r0..3} == A[q][k=quad*8+j].
// ---------------------------------------------------------------------------
__global__ __launch_bounds__(256) void k_prep_mem(const float* __restrict__ mem,
                                                  unsigned short* __restrict__ F) {
    __shared__ float part[64][4];
    __shared__ float scale[64];
    __shared__ unsigned short Tn[64 * SW];

    const int h  = blockIdx.y;
    const int tl = blockIdx.x;
    const int m0 = tl * 64;
    const int tid = threadIdx.x;
    const int r = tid >> 2;
    const int c = tid & 3;

    const float* src = mem + ((size_t)(h * M_SZ + m0 + r)) * HD + c * 16;
    float v[16];
    float ss = 0.f;
#pragma unroll
    for (int i = 0; i < 4; i++) {
        float4 f = reinterpret_cast<const float4*>(src)[i];
        v[4*i+0] = f.x; v[4*i+1] = f.y; v[4*i+2] = f.z; v[4*i+3] = f.w;
        ss += f.x*f.x + f.y*f.y + f.z*f.z + f.w*f.w;
    }
    part[r][c] = ss;
    __syncthreads();
    if (tid < 64) {
        float s = part[tid][0] + part[tid][1] + part[tid][2] + part[tid][3];
        scale[tid] = rsqrtf(s);
    }
    __syncthreads();
    const float sc = scale[r];

    U8 a, b;
#pragma unroll
    for (int i = 0; i < 8; i++) { a.us[i] = f2h(v[i] * sc); b.us[i] = f2h(v[8 + i] * sc); }
    *reinterpret_cast<uint4*>(&Tn[r * SW + c * 16])     = a.u4;
    *reinterpret_cast<uint4*>(&Tn[r * SW + c * 16 + 8]) = b.u4;
    __syncthreads();

    const int w = tid >> 6, lane = tid & 63;
    const int l15 = lane & 15, quad = lane >> 4;
    unsigned short* Fd = F + ((size_t)(h * 64 + tl) * 16) * 512;

    // QK A-frag chunks (permuted m)
#pragma unroll
    for (int i = 0; i < 2; i++) {
        const int ch = w * 2 + i, g = ch >> 1, s = ch & 1;
        const int mp = 32 * (g >> 1) + ((l15 >> 2) * 8) + 4 * (g & 1) + (l15 & 3);
        uint4 vv = *reinterpret_cast<const uint4*>(&Tn[mp * SW + s * 32 + quad * 8]);
        *reinterpret_cast<uint4*>(Fd + ch * 512 + lane * 8) = vv;
    }
    // PV B-frag chunks (physical m)
#pragma unroll
    for (int i = 0; i < 2; i++) {
        const int c2 = w * 2 + i, p = c2 >> 2, n = c2 & 3;
        U8 u;
#pragma unroll
        for (int j = 0; j < 8; j++)
            u.us[j] = Tn[(32 * p + quad * 8 + j) * SW + n * 16 + l15];
        *reinterpret_cast<uint4*>(Fd + (8 + c2) * 512 + lane * 8) = u.u4;
    }
}

// ---------------------------------------------------------------------------
// Kernel 2: q = xh @ Wh^T (f16 MFMA, 128x64 tile = one head), fused L2 norm,
// prescaled by log2(e). grid (32, 16) = 512 blocks -> 2 blocks/CU.
// 4 waves, each 32 rows x 64 cols.
// ---------------------------------------------------------------------------
__global__ __launch_bounds__(256, 2) void k_qproj(const unsigned short* __restrict__ xh,
                                                  const unsigned short* __restrict__ Wh,
                                                  unsigned short* __restrict__ qn) {
    __shared__ unsigned short As[128 * SW];
    __shared__ unsigned short Bs[64 * SW];

    const int b0 = blockIdx.x * 128;
    const int n0 = blockIdx.y * 64;     // == h*64
    const int t = threadIdx.x;
    const int w = t >> 6, lane = t & 63;
    const int l15 = lane & 15, quad = lane >> 4;

    f32x4 acc[2][4] = {};

    for (int kb = 0; kb < K_IN; kb += 64) {
        __syncthreads();
        {
            const unsigned short* px = xh + (size_t)(b0 + (t >> 1)) * K_IN + kb + (t & 1) * 32;
            const unsigned short* pw = Wh + (size_t)(n0 + (t >> 2)) * K_IN + kb + (t & 3) * 16;
            uint4 av[4];
#pragma unroll
            for (int i = 0; i < 4; i++) av[i] = reinterpret_cast<const uint4*>(px)[i];
            uint4 bv[2];
#pragma unroll
            for (int i = 0; i < 2; i++) bv[i] = reinterpret_cast<const uint4*>(pw)[i];
#pragma unroll
            for (int i = 0; i < 4; i++)
                *reinterpret_cast<uint4*>(&As[(t >> 1) * SW + (t & 1) * 32 + i * 8]) = av[i];
#pragma unroll
            for (int i = 0; i < 2; i++)
                *reinterpret_cast<uint4*>(&Bs[(t >> 2) * SW + (t & 3) * 16 + i * 8]) = bv[i];
        }
        __syncthreads();

#pragma unroll
        for (int s = 0; s < 2; s++) {
            f16x8 af[2];
#pragma unroll
            for (int qg = 0; qg < 2; qg++)
                af[qg] = ldsv8(&As[(w * 32 + qg * 16 + l15) * SW + s * 32 + quad * 8]);
#pragma unroll
            for (int g = 0; g < 4; g++) {
                f16x8 bf_ = ldsv8(&Bs[(g * 16 + l15) * SW + s * 32 + quad * 8]);
#pragma unroll
                for (int qg = 0; qg < 2; qg++)
                    acc[qg][g] = __builtin_amdgcn_mfma_f32_16x16x32_f16(af[qg], bf_, acc[qg][g], 0, 0, 0);
            }
        }
    }

    __syncthreads();
    unsigned short* Ct = As;   // 128 x SW
#pragma unroll
    for (int qg = 0; qg < 2; qg++) {
        float ssq[4];
#pragma unroll
        for (int r = 0; r < 4; r++) {
            float s = 0.f;
#pragma unroll
            for (int g = 0; g < 4; g++) s += acc[qg][g][r] * acc[qg][g][r];
            ssq[r] = s;
        }
#pragma unroll
        for (int mask = 1; mask <= 8; mask <<= 1)
#pragma unroll
            for (int r = 0; r < 4; r++) ssq[r] += __shfl_xor(ssq[r], mask, 64);
#pragma unroll
        for (int r = 0; r < 4; r++) {
            float inv = rsqrtf(ssq[r]) * LOG2E;
#pragma unroll
            for (int g = 0; g < 4; g++)
                Ct[(w * 32 + qg * 16 + quad * 4 + r) * SW + g * 16 + l15] = f2h(acc[qg][g][r] * inv);
        }
    }
    __syncthreads();

    const int row = t >> 1, half = (t & 1) * 32;
    unsigned short* dq = qn + (size_t)(b0 + row) * 1024 + n0 + half;
#pragma unroll
    for (int i = 0; i < 4; i++)
        reinterpret_cast<uint4*>(dq)[i] = *reinterpret_cast<const uint4*>(&Ct[row * SW + half + i * 8]);
}

// ---------------------------------------------------------------------------
// Kernel 3: fused attention. grid 512 (128 q x 1 head per block), 4 waves x 32 q.
// LDS double-buffered tile staging via global_load_lds (1 barrier/tile).
// QK: 16x16x32 (S^T = M.Q^T). PV: 16x16x32 with permuted-m A-frags (no shuffles).
// ---------------------------------------------------------------------------
__global__ __launch_bounds__(256, 2) void k_attn(const unsigned short* __restrict__ qn,
                                                 const unsigned short* __restrict__ F,
                                                 float* __restrict__ out) {
    __shared__ unsigned short buf[2][8192];   // 2 x 16 KB

    const int b = blockIdx.x;
    const int h  = 2 * (b & 7) + (b >> 8);    // XCD k gets heads {2k, 2k+1}
    const int b0 = ((b >> 3) & 31) * 128;
    const int t = threadIdx.x;
    const int w = t >> 6, lane = t & 63;
    const int l15 = lane & 15, quad = lane >> 4;

    // Q as B-operand of 16x16x32: lane holds Q[q=l15][d = s*32 + quad*8 + j]
    f16x8 qf[2][2];
#pragma unroll
    for (int qg = 0; qg < 2; qg++)
#pragma unroll
        for (int s = 0; s < 2; s++) {
            U8 u;
            u.u4 = *reinterpret_cast<const uint4*>(
                qn + (size_t)(b0 + w * 32 + qg * 16 + l15) * 1024 + h * 64 + s * 32 + quad * 8);
            qf[qg][s] = u.h8;
        }

    const unsigned short* Fh = F + (size_t)h * 64 * 8192;

    // prologue: stage tile 0 into buf[0] (each wave handles 4 of 16 chunks)
#pragma unroll
    for (int i = 0; i < 4; i++) {
        const int ch = w * 4 + i;
        gload_lds16(Fh + ch * 512 + lane * 8, &buf[0][ch * 512]);
    }

    f32x4 accO[2][4] = {};
    float lsum[2] = {0.f, 0.f};

    for (int tl = 0; tl < 64; ++tl) {
        __syncthreads();   // drains vmcnt -> buf[tl&1] complete; orders buffer reuse
        const int cur = tl & 1;

        if (tl + 1 < 64) {   // prefetch next tile into the other buffer
            const unsigned short* gn = Fh + (size_t)(tl + 1) * 8192;
#pragma unroll
            for (int i = 0; i < 4; i++) {
                const int ch = w * 4 + i;
                gload_lds16(gn + ch * 512 + lane * 8, &buf[cur ^ 1][ch * 512]);
            }
        }

        const unsigned short* lb = buf[cur];
        f16x8 am[8], bw[8];
#pragma unroll
        for (int ch = 0; ch < 8; ch++) am[ch] = ldsv8(&lb[ch * 512 + lane * 8]);
#pragma unroll
        for (int ch = 0; ch < 8; ch++) bw[ch] = ldsv8(&lb[(8 + ch) * 512 + lane * 8]);

#pragma unroll
        for (int qg = 0; qg < 2; qg++) {
#pragma unroll
            for (int p = 0; p < 2; p++) {
                // g = 2p (chunks 4p+0/1) and g = 2p+1 (chunks 4p+2/3)
                f32x4 s0 = {0.f, 0.f, 0.f, 0.f}, s1 = {0.f, 0.f, 0.f, 0.f};
                s0 = __builtin_amdgcn_mfma_f32_16x16x32_f16(am[4*p+0], qf[qg][0], s0, 0, 0, 0);
                s0 = __builtin_amdgcn_mfma_f32_16x16x32_f16(am[4*p+1], qf[qg][1], s0, 0, 0, 0);
                s1 = __builtin_amdgcn_mfma_f32_16x16x32_f16(am[4*p+2], qf[qg][0], s1, 0, 0, 0);
                s1 = __builtin_amdgcn_mfma_f32_16x16x32_f16(am[4*p+3], qf[qg][1], s1, 0, 0, 0);

                float p0 = EXP2F(s0[0]), p1 = EXP2F(s0[1]), p2 = EXP2F(s0[2]), p3 = EXP2F(s0[3]);
                float p4 = EXP2F(s1[0]), p5 = EXP2F(s1[1]), p6 = EXP2F(s1[2]), p7 = EXP2F(s1[3]);
                lsum[qg] += ((p0 + p1) + (p2 + p3)) + ((p4 + p5) + (p6 + p7));

                U8 pu;
#if __has_builtin(__builtin_amdgcn_cvt_pkrtz)
                pu.ui[0] = __builtin_bit_cast(unsigned int, __builtin_amdgcn_cvt_pkrtz(p0, p1));
                pu.ui[1] = __builtin_bit_cast(unsigned int, __builtin_amdgcn_cvt_pkrtz(p2, p3));
                pu.ui[2] = __builtin_bit_cast(unsigned int, __builtin_amdgcn_cvt_pkrtz(p4, p5));
                pu.ui[3] = __builtin_bit_cast(unsigned int, __builtin_amdgcn_cvt_pkrtz(p6, p7));
#else
                pu.us[0]=f2h(p0); pu.us[1]=f2h(p1); pu.us[2]=f2h(p2); pu.us[3]=f2h(p3);
                pu.us[4]=f2h(p4); pu.us[5]=f2h(p5); pu.us[6]=f2h(p6); pu.us[7]=f2h(p7);
#endif
                // pu.h8 == A[q=l15][k=quad*8+j] for m-block p (by construction)
#pragma unroll
                for (int n = 0; n < 4; n++)
                    accO[qg][n] = __builtin_amdgcn_mfma_f32_16x16x32_f16(pu.h8, bw[p * 4 + n], accO[qg][n], 0, 0, 0);
            }
        }
    }

    // epilogue: reduce lsum over quads (same l15), normalize, store
#pragma unroll
    for (int qg = 0; qg < 2; qg++) {
        float s = lsum[qg];
        s += __shfl_xor(s, 16, 64);
        s += __shfl_xor(s, 32, 64);
        float inv = 8.0f / s;    // sqrt(HEAD_DIM) = 8
#pragma unroll
        for (int r = 0; r < 4; r++) {
            float iv = __shfl(inv, quad * 4 + r, 64);
            float* po = out + (size_t)(b0 + w * 32 + qg * 16 + quad * 4 + r) * 1024 + h * 64;
#pragma unroll
            for (int n = 0; n < 4; n++)
                po[n * 16 + l15] = accO[qg][n][r] * iv;
        }
    }
}

// ---------------------------------------------------------------------------
extern "C" void kernel_launch(void* const* d_in, const int* in_sizes, int n_in,
                              void* d_out, int out_size, void* d_ws, size_t ws_size,
                              hipStream_t stream) {
    (void)in_sizes; (void)n_in; (void)out_size; (void)ws_size;
    const float* x   = (const float*)d_in[0];
    const float* Wq  = (const float*)d_in[1];
    const float* mem = (const float*)d_in[2];
    float* out = (float*)d_out;

    unsigned short* qn = (unsigned short*)d_ws;                 // 8 MB
    unsigned short* F  = qn + (size_t)B_SZ * 1024;              // 16 MB (frag-ordered)
    unsigned short* xh = F  + (size_t)HEADS * 64 * 16 * 512;    // 8 MB
    unsigned short* Wh = xh + (size_t)B_SZ * K_IN;              // 2 MB  (total 34 MB)

    k_conv    <<<2560, 256, 0, stream>>>(x, Wq, xh, Wh);
    k_prep_mem<<<dim3(64, 16), 256, 0, stream>>>(mem, F);
    k_qproj   <<<dim3(32, 16), 256, 0, stream>>>(xh, Wh, qn);
    k_attn    <<<512, 256, 0, stream>>>(qn, F, out);
}